// Round 1
// baseline (529.235 us; speedup 1.0000x reference)
//
#include <hip/hip_runtime.h>
#include <hip/hip_bf16.h>

typedef __bf16 bf16x8 __attribute__((ext_vector_type(8)));
typedef __bf16 bf16x4 __attribute__((ext_vector_type(4)));
typedef float  f32x4  __attribute__((ext_vector_type(4)));

// Problem constants
#define BB 256
#define HD 1024
#define ED 512
#define KX 1536        // H + E
#define G4 4096        // 4*H

// d_out offsets (floats)
#define O_FINAL 0
#define O_H     512
#define O_C     1049088      // 512 + 4*256*1024
#define O_NORM  2097664      // O_C + 4*256*1024

// ---------------- scores: sc[b*256 + pos] = dot(AO[pos,b,:], w_y) ----------------
// (h_top@w_h + b_attn cancels in softmax -> skipped)
__global__ __launch_bounds__(256) void k_scores(const float* __restrict__ AO,
                                                const float* __restrict__ Wattn,
                                                float* __restrict__ sc) {
  const int lane = threadIdx.x & 63, wave = threadIdx.x >> 6;
  const float* wy = Wattn + 1024;
  float4 wv[4];
#pragma unroll
  for (int q = 0; q < 4; ++q) wv[q] = *(const float4*)(wy + lane * 4 + 256 * q);
  const int row0 = (blockIdx.x * 4 + wave) * 4;
  float acc[4];
#pragma unroll
  for (int rr = 0; rr < 4; ++rr) {
    const float4* rp = (const float4*)(AO + (size_t)(row0 + rr) * 1024);
    float a = 0.f;
#pragma unroll
    for (int q = 0; q < 4; ++q) {
      float4 v = rp[lane + 64 * q];
      a += v.x * wv[q].x + v.y * wv[q].y + v.z * wv[q].z + v.w * wv[q].w;
    }
    acc[rr] = a;
  }
#pragma unroll
  for (int rr = 0; rr < 4; ++rr) {
    float a = acc[rr];
#pragma unroll
    for (int off = 32; off; off >>= 1) a += __shfl_xor(a, off, 64);
    if (lane == 0) {
      int row = row0 + rr;                       // row = pos*256 + b
      sc[(row & 255) * 256 + (row >> 8)] = a;    // [b][pos]
    }
  }
}

// ---------------- softmax per batch row ----------------
__global__ __launch_bounds__(256) void k_softmax(const float* __restrict__ sc,
                                                 float* __restrict__ norm_out) {
  __shared__ float red[4];
  const int b = blockIdx.x, t = threadIdx.x, lane = t & 63, wave = t >> 6;
  float s = sc[b * 256 + t];
  float m = s;
#pragma unroll
  for (int off = 32; off; off >>= 1) m = fmaxf(m, __shfl_xor(m, off, 64));
  if (lane == 0) red[wave] = m;
  __syncthreads();
  m = fmaxf(fmaxf(red[0], red[1]), fmaxf(red[2], red[3]));
  float e = __expf(s - m);
  float sum = e;
#pragma unroll
  for (int off = 32; off; off >>= 1) sum += __shfl_xor(sum, off, 64);
  __syncthreads();
  if (lane == 0) red[wave] = sum;
  __syncthreads();
  sum = red[0] + red[1] + red[2] + red[3];
  norm_out[b * 256 + t] = e / sum;
}

// ---------------- h0 fp32 -> bf16 ----------------
__global__ __launch_bounds__(256) void k_cvt_h0(const float* __restrict__ h0,
                                                __bf16* __restrict__ h0b) {
  const int idx = blockIdx.x * 256 + threadIdx.x;   // float4 index, 262144 total
  float4 v = ((const float4*)h0)[idx];
  bf16x4 o;
  o[0] = (__bf16)v.x; o[1] = (__bf16)v.y; o[2] = (__bf16)v.z; o[3] = (__bf16)v.w;
  ((bf16x4*)h0b)[idx] = o;
}

// ---------------- build x = [8*applied_last | relu(emb)] in bf16 ----------------
__global__ __launch_bounds__(256) void k_buildx(const float* __restrict__ AO,
                                                const float* __restrict__ norm,
                                                const float* __restrict__ inp,
                                                const float* __restrict__ Wemb,
                                                const float* __restrict__ bemb,
                                                __bf16* __restrict__ x) {
  if (blockIdx.x < 1024) {
    const int b = blockIdx.x >> 2, ch = blockIdx.x & 3;
    __shared__ float w[32];
    if (threadIdx.x < 32) w[threadIdx.x] = norm[b * 256 + 224 + threadIdx.x];
    __syncthreads();
    const int h = ch * 256 + threadIdx.x;
    float acc = 0.f;
#pragma unroll 8
    for (int i = 0; i < 32; ++i)
      acc += w[i] * AO[((size_t)(224 + i) * 256 + b) * 1024 + h];
    x[(size_t)b * KX + h] = (__bf16)(8.0f * acc);
  } else {
    const int idx = (blockIdx.x - 1024) * 256 + threadIdx.x;  // 0..131071
    const int b = idx >> 9, j = idx & 511;
    float e = inp[b * 2] * Wemb[j * 2] + inp[b * 2 + 1] * Wemb[j * 2 + 1] + bemb[j];
    x[(size_t)b * KX + 1024 + j] = (__bf16)fmaxf(e, 0.f);
  }
}

// ---------------- LSTM pre-activation GEMM: G = A1@W1^T + A2@W2^T ----------------
// block: 512 thr = 8 waves; tile 256 rows x 32 cols; grid 128
__device__ __forceinline__ void gemm_acc(const __bf16* __restrict__ A,
                                         const float* __restrict__ W, int K,
                                         int rowbase, int colbase, int lane,
                                         f32x4 acc[2][2]) {
  const int r0 = lane & 15;
  const int kl = (lane >> 4) << 3;
  const __bf16* a0 = A + (size_t)(rowbase + r0) * K + kl;
  const __bf16* a1 = a0 + (size_t)16 * K;
  const float* w0 = W + (size_t)(colbase + r0) * K + kl;
  const float* w1 = w0 + (size_t)16 * K;
#pragma unroll 2
  for (int k0 = 0; k0 < K; k0 += 32) {
    bf16x8 a[2];
    a[0] = *(const bf16x8*)(a0 + k0);
    a[1] = *(const bf16x8*)(a1 + k0);
    bf16x8 bb[2];
    {
      float4 f0 = *(const float4*)(w0 + k0), f1 = *(const float4*)(w0 + k0 + 4);
      bf16x8 t;
      t[0] = (__bf16)f0.x; t[1] = (__bf16)f0.y; t[2] = (__bf16)f0.z; t[3] = (__bf16)f0.w;
      t[4] = (__bf16)f1.x; t[5] = (__bf16)f1.y; t[6] = (__bf16)f1.z; t[7] = (__bf16)f1.w;
      bb[0] = t;
    }
    {
      float4 f0 = *(const float4*)(w1 + k0), f1 = *(const float4*)(w1 + k0 + 4);
      bf16x8 t;
      t[0] = (__bf16)f0.x; t[1] = (__bf16)f0.y; t[2] = (__bf16)f0.z; t[3] = (__bf16)f0.w;
      t[4] = (__bf16)f1.x; t[5] = (__bf16)f1.y; t[6] = (__bf16)f1.z; t[7] = (__bf16)f1.w;
      bb[1] = t;
    }
#pragma unroll
    for (int r = 0; r < 2; ++r)
#pragma unroll
      for (int c = 0; c < 2; ++c)
        acc[r][c] = __builtin_amdgcn_mfma_f32_16x16x32_bf16(a[r], bb[c], acc[r][c], 0, 0, 0);
  }
}

__global__ __launch_bounds__(512) void k_gemm(const __bf16* __restrict__ A1,
                                              const float* __restrict__ W1, int K1,
                                              const __bf16* __restrict__ A2,
                                              const float* __restrict__ W2, int K2,
                                              float* __restrict__ G) {
  const int lane = threadIdx.x & 63, wave = threadIdx.x >> 6;
  const int rowbase = wave * 32, colbase = blockIdx.x * 32;
  f32x4 acc[2][2] = {};
  gemm_acc(A1, W1, K1, rowbase, colbase, lane, acc);
  gemm_acc(A2, W2, K2, rowbase, colbase, lane, acc);
#pragma unroll
  for (int r = 0; r < 2; ++r)
#pragma unroll
    for (int c = 0; c < 2; ++c)
#pragma unroll
      for (int q = 0; q < 4; ++q) {
        int row = rowbase + r * 16 + ((lane >> 4) << 2) + q;
        int col = colbase + c * 16 + (lane & 15);
        G[(size_t)row * G4 + col] = acc[r][c][q];
      }
}

// ---------------- gates ----------------
__global__ __launch_bounds__(256) void k_gates(const float* __restrict__ G,
                                               const float* __restrict__ c0,
                                               const float* __restrict__ bih,
                                               const float* __restrict__ bhh,
                                               float* __restrict__ h_out,
                                               float* __restrict__ c_out,
                                               __bf16* __restrict__ hb) {
  const int idx = blockIdx.x * 256 + threadIdx.x;   // 0..262143
  const int b = idx >> 10, j = idx & 1023;
  const float* gr = G + (size_t)b * G4;
  float gi = gr[j]        + bih[j]        + bhh[j];
  float gf = gr[1024 + j] + bih[1024 + j] + bhh[1024 + j];
  float gg = gr[2048 + j] + bih[2048 + j] + bhh[2048 + j];
  float go = gr[3072 + j] + bih[3072 + j] + bhh[3072 + j];
  float si = 1.f / (1.f + __expf(-gi));
  float sf = 1.f / (1.f + __expf(-gf));
  float so = 1.f / (1.f + __expf(-go));
  float c2 = sf * c0[idx] + si * tanhf(gg);
  float h2 = so * tanhf(c2);
  h_out[idx] = h2;
  c_out[idx] = c2;
  hb[idx] = (__bf16)h2;
}

// ---------------- final output: out[b,o] = h3[b,:]@W_out[o,:] + b_out ----------------
__global__ __launch_bounds__(256) void k_final(const float* __restrict__ h3,
                                               const float* __restrict__ Wout,
                                               const float* __restrict__ bout,
                                               float* __restrict__ out) {
  const int lane = threadIdx.x & 63, wave = threadIdx.x >> 6;
  const int b = blockIdx.x * 4 + wave;
  const float4* hp = (const float4*)(h3 + (size_t)b * 1024);
  const float4* w0 = (const float4*)Wout;
  const float4* w1 = (const float4*)(Wout + 1024);
  float a0 = 0.f, a1 = 0.f;
#pragma unroll
  for (int q = 0; q < 4; ++q) {
    float4 hv = hp[lane + 64 * q];
    float4 v0 = w0[lane + 64 * q];
    float4 v1 = w1[lane + 64 * q];
    a0 += hv.x * v0.x + hv.y * v0.y + hv.z * v0.z + hv.w * v0.w;
    a1 += hv.x * v1.x + hv.y * v1.y + hv.z * v1.z + hv.w * v1.w;
  }
#pragma unroll
  for (int off = 32; off; off >>= 1) {
    a0 += __shfl_xor(a0, off, 64);
    a1 += __shfl_xor(a1, off, 64);
  }
  if (lane == 0) {
    out[b * 2]     = a0 + bout[0];
    out[b * 2 + 1] = a1 + bout[1];
  }
}

extern "C" void kernel_launch(void* const* d_in, const int* in_sizes, int n_in,
                              void* d_out, int out_size, void* d_ws, size_t ws_size,
                              hipStream_t stream) {
  const float* inp    = (const float*)d_in[0];
  const float* h0     = (const float*)d_in[1];
  const float* c0     = (const float*)d_in[2];
  const float* AO     = (const float*)d_in[3];
  const float* Wemb   = (const float*)d_in[4];
  const float* bemb   = (const float*)d_in[5];
  const float* Wattn  = (const float*)d_in[6];
  // d_in[7] = b_attn (cancels in softmax)
  const float* Wih0   = (const float*)d_in[8];
  const float* Whh0   = (const float*)d_in[9];
  const float* bih0   = (const float*)d_in[10];
  const float* bhh0   = (const float*)d_in[11];
  const float* Wih_r  = (const float*)d_in[12];
  const float* Whh_r  = (const float*)d_in[13];
  const float* bih_r  = (const float*)d_in[14];
  const float* bhh_r  = (const float*)d_in[15];
  const float* Wout   = (const float*)d_in[16];
  const float* bout   = (const float*)d_in[17];

  float* out = (float*)d_out;
  char* ws = (char*)d_ws;

  float*  sc  = (float*)(ws + 0);                 // 256 KB
  float*  G   = (float*)(ws + 262144);            // 4 MB
  __bf16* xb  = (__bf16*)(ws + 4456448);          // 768 KB
  __bf16* h0b = (__bf16*)(ws + 5242880);          // 2 MB
  __bf16* hb  = (__bf16*)(ws + 7340032);          // 2 MB (4 layers x 512KB)

  k_cvt_h0<<<1024, 256, 0, stream>>>(h0, h0b);
  k_scores<<<4096, 256, 0, stream>>>(AO, Wattn, sc);
  k_softmax<<<256, 256, 0, stream>>>(sc, out + O_NORM);
  k_buildx<<<1536, 256, 0, stream>>>(AO, out + O_NORM, inp, Wemb, bemb, xb);

  for (int l = 0; l < 4; ++l) {
    const __bf16* A1 = (l == 0) ? xb : (hb + (size_t)(l - 1) * 262144);
    const float*  W1 = (l == 0) ? Wih0 : (Wih_r + (size_t)(l - 1) * 4194304);
    const int     K1 = (l == 0) ? KX : 1024;
    const __bf16* A2 = h0b + (size_t)l * 262144;
    const float*  W2 = (l == 0) ? Whh0 : (Whh_r + (size_t)(l - 1) * 4194304);
    const float*  bih = (l == 0) ? bih0 : (bih_r + (size_t)(l - 1) * 4096);
    const float*  bhh = (l == 0) ? bhh0 : (bhh_r + (size_t)(l - 1) * 4096);

    k_gemm<<<128, 512, 0, stream>>>(A1, W1, K1, A2, W2, 1024, G);
    k_gates<<<1024, 256, 0, stream>>>(G, c0 + (size_t)l * 262144, bih, bhh,
                                      out + O_H + (size_t)l * 262144,
                                      out + O_C + (size_t)l * 262144,
                                      hb + (size_t)l * 262144);
  }

  k_final<<<64, 256, 0, stream>>>(out + O_H + 3 * 262144, Wout, bout, out + O_FINAL);
}

// Round 2
// 303.807 us; speedup vs baseline: 1.7420x; 1.7420x over previous
//
#include <hip/hip_runtime.h>
#include <hip/hip_bf16.h>

typedef __bf16 bf16x8 __attribute__((ext_vector_type(8)));
typedef __bf16 bf16x4 __attribute__((ext_vector_type(4)));
typedef float  f32x4  __attribute__((ext_vector_type(4)));

#define KX 1536        // H + E
#define G4 4096        // 4*H

// d_out offsets (floats)
#define O_FINAL 0
#define O_H     512
#define O_C     1049088      // 512 + 4*256*1024
#define O_NORM  2097664      // O_C + 4*256*1024

// ---------------- scores: sc[b*256 + pos] = dot(AO[pos,b,:], w_y) ----------------
// (h_top@w_h + b_attn are per-b row constants -> cancel in softmax -> skipped)
__global__ __launch_bounds__(256) void k_scores(const float* __restrict__ AO,
                                                const float* __restrict__ Wattn,
                                                float* __restrict__ sc) {
  const int lane = threadIdx.x & 63, wave = threadIdx.x >> 6;
  const float* wy = Wattn + 1024;
  float4 wv[4];
#pragma unroll
  for (int q = 0; q < 4; ++q) wv[q] = *(const float4*)(wy + lane * 4 + 256 * q);
  const int row0 = (blockIdx.x * 4 + wave) * 4;
  float acc[4];
#pragma unroll
  for (int rr = 0; rr < 4; ++rr) {
    const float4* rp = (const float4*)(AO + (size_t)(row0 + rr) * 1024);
    float a = 0.f;
#pragma unroll
    for (int q = 0; q < 4; ++q) {
      float4 v = rp[lane + 64 * q];
      a += v.x * wv[q].x + v.y * wv[q].y + v.z * wv[q].z + v.w * wv[q].w;
    }
    acc[rr] = a;
  }
#pragma unroll
  for (int rr = 0; rr < 4; ++rr) {
    float a = acc[rr];
#pragma unroll
    for (int off = 32; off; off >>= 1) a += __shfl_xor(a, off, 64);
    if (lane == 0) {
      int row = row0 + rr;                       // row = pos*256 + b
      sc[(row & 255) * 256 + (row >> 8)] = a;    // [b][pos]
    }
  }
}

// ---------------- h0 fp32 -> bf16 ----------------
__global__ __launch_bounds__(256) void k_cvt_h0(const float* __restrict__ h0,
                                                __bf16* __restrict__ h0b) {
  const int idx = blockIdx.x * 256 + threadIdx.x;   // float4 index, 262144 total
  float4 v = ((const float4*)h0)[idx];
  bf16x4 o;
  o[0] = (__bf16)v.x; o[1] = (__bf16)v.y; o[2] = (__bf16)v.z; o[3] = (__bf16)v.w;
  ((bf16x4*)h0b)[idx] = o;
}

// ---------------- fused softmax + applied_last + embedding: builds x (bf16) ----------------
__global__ __launch_bounds__(256) void k_smx(const float* __restrict__ sc,
                                             const float* __restrict__ AO,
                                             const float* __restrict__ inp,
                                             const float* __restrict__ Wemb,
                                             const float* __restrict__ bemb,
                                             float* __restrict__ norm_out,
                                             __bf16* __restrict__ x) {
  __shared__ float red[4];
  __shared__ float wsm[32];
  const int b = blockIdx.x, t = threadIdx.x, lane = t & 63, wave = t >> 6;
  float s = sc[b * 256 + t];
  float m = s;
#pragma unroll
  for (int off = 32; off; off >>= 1) m = fmaxf(m, __shfl_xor(m, off, 64));
  if (lane == 0) red[wave] = m;
  __syncthreads();
  m = fmaxf(fmaxf(red[0], red[1]), fmaxf(red[2], red[3]));
  float e = __expf(s - m);
  float sum = e;
#pragma unroll
  for (int off = 32; off; off >>= 1) sum += __shfl_xor(sum, off, 64);
  __syncthreads();
  if (lane == 0) red[wave] = sum;
  __syncthreads();
  sum = red[0] + red[1] + red[2] + red[3];
  float nv = e / sum;
  norm_out[b * 256 + t] = nv;
  if (t >= 224) wsm[t - 224] = nv;
  __syncthreads();
  // applied_last: x[b, 0..1023] = 8 * sum_i wsm[i] * AO[224+i, b, :]
  float acc[4] = {0.f, 0.f, 0.f, 0.f};
  const float* base = AO + ((size_t)224 * 256 + b) * 1024;
#pragma unroll 4
  for (int i = 0; i < 32; ++i) {
    float w = wsm[i];
    const float* rp = base + (size_t)i * 256 * 1024;
#pragma unroll
    for (int q = 0; q < 4; ++q) acc[q] += w * rp[t + 256 * q];
  }
#pragma unroll
  for (int q = 0; q < 4; ++q) x[(size_t)b * KX + t + 256 * q] = (__bf16)(8.0f * acc[q]);
  // embedding: x[b, 1024..1535] = relu(inp[b]@Wemb.T + bemb)
  float i0 = inp[b * 2], i1 = inp[b * 2 + 1];
#pragma unroll
  for (int r = 0; r < 2; ++r) {
    int j = t + 256 * r;
    float e2 = i0 * Wemb[j * 2] + i1 * Wemb[j * 2 + 1] + bemb[j];
    x[(size_t)b * KX + 1024 + j] = (__bf16)fmaxf(e2, 0.f);
  }
}

// ---------------- MFMA core: acc += A[rows, k0..k0+K) @ W[cols, ...].T ----------------
// A bf16 row-stride ASTR; W fp32 row-stride WSTR (converted inline); 2x2 16x16 frags
template<int K, int ASTR, int WSTR>
__device__ __forceinline__ void gemm_acc(const __bf16* __restrict__ A,
                                         const float* __restrict__ W,
                                         int rowbase, int colbase, int lane,
                                         f32x4 acc[2][2]) {
  const int r0 = lane & 15;
  const int kl = (lane >> 4) << 3;
  const __bf16* a0 = A + (size_t)(rowbase + r0) * ASTR + kl;
  const __bf16* a1 = a0 + (size_t)16 * ASTR;
  const float* w0 = W + (size_t)(colbase + r0) * WSTR + kl;
  const float* w1 = w0 + (size_t)16 * WSTR;
#pragma unroll 4
  for (int k0 = 0; k0 < K; k0 += 32) {
    bf16x8 a[2];
    a[0] = *(const bf16x8*)(a0 + k0);
    a[1] = *(const bf16x8*)(a1 + k0);
    bf16x8 bb[2];
    {
      float4 f0 = *(const float4*)(w0 + k0), f1 = *(const float4*)(w0 + k0 + 4);
      bf16x8 tt;
      tt[0] = (__bf16)f0.x; tt[1] = (__bf16)f0.y; tt[2] = (__bf16)f0.z; tt[3] = (__bf16)f0.w;
      tt[4] = (__bf16)f1.x; tt[5] = (__bf16)f1.y; tt[6] = (__bf16)f1.z; tt[7] = (__bf16)f1.w;
      bb[0] = tt;
    }
    {
      float4 f0 = *(const float4*)(w1 + k0), f1 = *(const float4*)(w1 + k0 + 4);
      bf16x8 tt;
      tt[0] = (__bf16)f0.x; tt[1] = (__bf16)f0.y; tt[2] = (__bf16)f0.z; tt[3] = (__bf16)f0.w;
      tt[4] = (__bf16)f1.x; tt[5] = (__bf16)f1.y; tt[6] = (__bf16)f1.z; tt[7] = (__bf16)f1.w;
      bb[1] = tt;
    }
#pragma unroll
    for (int r = 0; r < 2; ++r)
#pragma unroll
      for (int c = 0; c < 2; ++c)
        acc[r][c] = __builtin_amdgcn_mfma_f32_16x16x32_bf16(a[r], bb[c], acc[r][c], 0, 0, 0);
  }
}

// ---------------- Gh[l] = h0b[l] @ Whh[l].T + bih + bhh  (all layers, parallel) ----------------
__global__ __launch_bounds__(512) void k_gh(const __bf16* __restrict__ h0b,
                                            const float* __restrict__ Whh0,
                                            const float* __restrict__ Whh_r,
                                            const float* __restrict__ bih0,
                                            const float* __restrict__ bhh0,
                                            const float* __restrict__ bih_r,
                                            const float* __restrict__ bhh_r,
                                            float* __restrict__ Gh) {
  const int lane = threadIdx.x & 63, wave = threadIdx.x >> 6;
  const int l = blockIdx.x >> 7, cb = blockIdx.x & 127;
  const __bf16* A = h0b + (size_t)l * 262144;
  const float* W  = (l == 0) ? Whh0 : (Whh_r + (size_t)(l - 1) * 4194304);
  const float* bi = (l == 0) ? bih0 : (bih_r + (size_t)(l - 1) * 4096);
  const float* bh = (l == 0) ? bhh0 : (bhh_r + (size_t)(l - 1) * 4096);
  float* Go = Gh + (size_t)l * 1048576;
  const int rowbase = wave * 32, colbase = cb * 32;
  f32x4 acc[2][2] = {};
  gemm_acc<1024, 1024, 1024>(A, W, rowbase, colbase, lane, acc);
#pragma unroll
  for (int r = 0; r < 2; ++r)
#pragma unroll
    for (int c = 0; c < 2; ++c)
#pragma unroll
      for (int q = 0; q < 4; ++q) {
        int row = rowbase + r * 16 + ((lane >> 4) << 2) + q;
        int col = colbase + c * 16 + (lane & 15);
        Go[(size_t)row * G4 + col] = acc[r][c][q] + bi[col] + bh[col];
      }
}

// ---------------- serial per-layer gemm, K-split x2: Gp[kh] = A[:,kh] @ Wih[:,kh].T ----------------
template<int KHALF, int KFULL>
__global__ __launch_bounds__(512) void k_lstm(const __bf16* __restrict__ A,
                                              const float* __restrict__ Wih,
                                              float* __restrict__ Gp) {
  const int lane = threadIdx.x & 63, wave = threadIdx.x >> 6;
  const int cb = blockIdx.x & 127, kh = blockIdx.x >> 7;
  const __bf16* Ao = A + (size_t)kh * KHALF;
  const float*  Wo = Wih + (size_t)kh * KHALF;
  float* Go = Gp + (size_t)kh * 1048576;
  const int rowbase = wave * 32, colbase = cb * 32;
  f32x4 acc[2][2] = {};
  gemm_acc<KHALF, KFULL, KFULL>(Ao, Wo, rowbase, colbase, lane, acc);
#pragma unroll
  for (int r = 0; r < 2; ++r)
#pragma unroll
    for (int c = 0; c < 2; ++c)
#pragma unroll
      for (int q = 0; q < 4; ++q) {
        int row = rowbase + r * 16 + ((lane >> 4) << 2) + q;
        int col = colbase + c * 16 + (lane & 15);
        Go[(size_t)row * G4 + col] = acc[r][c][q];
      }
}

// ---------------- gates: g = Gp0 + Gp1 + Gh (biases already in Gh) ----------------
__global__ __launch_bounds__(256) void k_gates(const float* __restrict__ Gp,
                                               const float* __restrict__ Gh,
                                               const float* __restrict__ c0,
                                               float* __restrict__ h_out,
                                               float* __restrict__ c_out,
                                               __bf16* __restrict__ hb) {
  const int idx = blockIdx.x * 256 + threadIdx.x;   // 0..262143
  const int b = idx >> 10, j = idx & 1023;
  const float* g0 = Gp + (size_t)b * G4;
  const float* g1 = g0 + 1048576;
  const float* gh = Gh + (size_t)b * G4;
  float gi = g0[j]        + g1[j]        + gh[j];
  float gf = g0[1024 + j] + g1[1024 + j] + gh[1024 + j];
  float gg = g0[2048 + j] + g1[2048 + j] + gh[2048 + j];
  float go = g0[3072 + j] + g1[3072 + j] + gh[3072 + j];
  float si = 1.f / (1.f + __expf(-gi));
  float sf = 1.f / (1.f + __expf(-gf));
  float so = 1.f / (1.f + __expf(-go));
  float c2 = sf * c0[idx] + si * tanhf(gg);
  float h2 = so * tanhf(c2);
  h_out[idx] = h2;
  c_out[idx] = c2;
  hb[idx] = (__bf16)h2;
}

// ---------------- final output ----------------
__global__ __launch_bounds__(256) void k_final(const float* __restrict__ h3,
                                               const float* __restrict__ Wout,
                                               const float* __restrict__ bout,
                                               float* __restrict__ out) {
  const int lane = threadIdx.x & 63, wave = threadIdx.x >> 6;
  const int b = blockIdx.x * 4 + wave;
  const float4* hp = (const float4*)(h3 + (size_t)b * 1024);
  const float4* w0 = (const float4*)Wout;
  const float4* w1 = (const float4*)(Wout + 1024);
  float a0 = 0.f, a1 = 0.f;
#pragma unroll
  for (int q = 0; q < 4; ++q) {
    float4 hv = hp[lane + 64 * q];
    float4 v0 = w0[lane + 64 * q];
    float4 v1 = w1[lane + 64 * q];
    a0 += hv.x * v0.x + hv.y * v0.y + hv.z * v0.z + hv.w * v0.w;
    a1 += hv.x * v1.x + hv.y * v1.y + hv.z * v1.z + hv.w * v1.w;
  }
#pragma unroll
  for (int off = 32; off; off >>= 1) {
    a0 += __shfl_xor(a0, off, 64);
    a1 += __shfl_xor(a1, off, 64);
  }
  if (lane == 0) {
    out[b * 2]     = a0 + bout[0];
    out[b * 2 + 1] = a1 + bout[1];
  }
}

extern "C" void kernel_launch(void* const* d_in, const int* in_sizes, int n_in,
                              void* d_out, int out_size, void* d_ws, size_t ws_size,
                              hipStream_t stream) {
  const float* inp    = (const float*)d_in[0];
  const float* h0     = (const float*)d_in[1];
  const float* c0     = (const float*)d_in[2];
  const float* AO     = (const float*)d_in[3];
  const float* Wemb   = (const float*)d_in[4];
  const float* bemb   = (const float*)d_in[5];
  const float* Wattn  = (const float*)d_in[6];
  // d_in[7] = b_attn (cancels in softmax)
  const float* Wih0   = (const float*)d_in[8];
  const float* Whh0   = (const float*)d_in[9];
  const float* bih0   = (const float*)d_in[10];
  const float* bhh0   = (const float*)d_in[11];
  const float* Wih_r  = (const float*)d_in[12];
  const float* Whh_r  = (const float*)d_in[13];
  const float* bih_r  = (const float*)d_in[14];
  const float* bhh_r  = (const float*)d_in[15];
  const float* Wout   = (const float*)d_in[16];
  const float* bout   = (const float*)d_in[17];

  float* out = (float*)d_out;
  char* ws = (char*)d_ws;

  float*  sc  = (float*)(ws + 0);                  // 256 KB
  float*  G   = (float*)(ws + (1u << 18));         // 8 MB (2 K-split partials)
  float*  Gh  = (float*)(ws + 8912896);            // 16 MB (4 layers)
  __bf16* xb  = (__bf16*)(ws + 25690112);          // 768 KB
  __bf16* h0b = (__bf16*)(ws + 26476544);          // 2 MB
  __bf16* hb  = (__bf16*)(ws + 28573696);          // 2 MB (4 layers x 512 KB)

  k_cvt_h0<<<1024, 256, 0, stream>>>(h0, h0b);
  k_scores<<<4096, 256, 0, stream>>>(AO, Wattn, sc);
  k_gh<<<512, 512, 0, stream>>>(h0b, Whh0, Whh_r, bih0, bhh0, bih_r, bhh_r, Gh);
  k_smx<<<256, 256, 0, stream>>>(sc, AO, inp, Wemb, bemb, out + O_NORM, xb);

  for (int l = 0; l < 4; ++l) {
    const __bf16* A1 = (l == 0) ? xb : (hb + (size_t)(l - 1) * 262144);
    if (l == 0)
      k_lstm<768, 1536><<<256, 512, 0, stream>>>(A1, Wih0, G);
    else
      k_lstm<512, 1024><<<256, 512, 0, stream>>>(A1, Wih_r + (size_t)(l - 1) * 4194304, G);
    k_gates<<<1024, 256, 0, stream>>>(G, Gh + (size_t)l * 1048576,
                                      c0 + (size_t)l * 262144,
                                      out + O_H + (size_t)l * 262144,
                                      out + O_C + (size_t)l * 262144,
                                      hb + (size_t)l * 262144);
  }

  k_final<<<64, 256, 0, stream>>>(out + O_H + 3 * 262144, Wout, bout, out + O_FINAL);
}

// Round 3
// 181.229 us; speedup vs baseline: 2.9203x; 1.6764x over previous
//
#include <hip/hip_runtime.h>
#include <hip/hip_bf16.h>

typedef __bf16 bf16x8 __attribute__((ext_vector_type(8)));
typedef __bf16 bf16x4 __attribute__((ext_vector_type(4)));
typedef float  f32x4  __attribute__((ext_vector_type(4)));

#define KX 1536        // H + E
#define G4 4096        // 4*H

// d_out offsets (floats)
#define O_FINAL 0
#define O_H     512
#define O_C     1049088      // 512 + 4*256*1024
#define O_NORM  2097664      // O_C + 4*256*1024

// ============ staged tile-GEMM core ============
// Block (512 thr, 8 waves) computes a 64-row x (16 cols x 4 gates) tile of
// A[256 x K] @ W[4096 x K]^T.  Wave w: rf=w&3 -> rows r0+rf*16..+15,
// gg=w>>2 -> gates {2gg, 2gg+1}.  Output: acc[2] (16x16 frag per gate).
// W is fp32 (converted inline to bf16 during LDS staging), A is bf16.
// LDS tiles are XOR-swizzled (byte ^= (row&7)<<4) so ds_read_b128 frag
// reads (16 lanes at 128B row stride) don't 16-way bank-conflict.
template<int K>
__device__ __forceinline__ void tile_gemm(const __bf16* __restrict__ A,
                                          const float* __restrict__ W,
                                          int r0, int j0,
                                          __bf16* __restrict__ At,
                                          __bf16* __restrict__ Wt,
                                          f32x4 acc[2]) {
  const int t = threadIdx.x;
  const int lane = t & 63, wave = t >> 6;
  const int rf = wave & 3, gg = wave >> 2;
  const int tr = t >> 3, chunk = t & 7;          // staging: row 0..63, 8-float chunk
  const int wrow = (tr >> 4) * 1024 + j0 + (tr & 15);
  const float*  wsrc = W + (size_t)wrow * K + chunk * 8;
  const __bf16* asrc = A + (size_t)(r0 + tr) * K + chunk * 8;
  const int sw_off = (chunk ^ (tr & 7)) << 4;    // swizzled byte offset in row
  char* wdst = (char*)Wt + tr * 128 + sw_off;
  char* adst = (char*)At + tr * 128 + sw_off;
  const int a_tr  = rf * 16 + (lane & 15);
  const int w_tr0 = gg * 32 + (lane & 15);
  const int w_tr1 = w_tr0 + 16;
  const int ksel  = lane >> 4;                   // 0..3

  // prologue global load (k0 = 0)
  float4 wreg0 = *(const float4*)wsrc;
  float4 wreg1 = *(const float4*)(wsrc + 4);
  bf16x8 areg  = *(const bf16x8*)asrc;

  constexpr int NK = K / 64;
#pragma unroll 2
  for (int step = 0; step < NK; ++step) {
    __syncthreads();                             // prior tile fully consumed
    bf16x8 wv;
    wv[0] = (__bf16)wreg0.x; wv[1] = (__bf16)wreg0.y;
    wv[2] = (__bf16)wreg0.z; wv[3] = (__bf16)wreg0.w;
    wv[4] = (__bf16)wreg1.x; wv[5] = (__bf16)wreg1.y;
    wv[6] = (__bf16)wreg1.z; wv[7] = (__bf16)wreg1.w;
    *(bf16x8*)wdst = wv;
    *(bf16x8*)adst = areg;
    __syncthreads();
    if (step + 1 < NK) {                         // prefetch next k-tile (hides under MFMA)
      wreg0 = *(const float4*)(wsrc + (step + 1) * 64);
      wreg1 = *(const float4*)(wsrc + (step + 1) * 64 + 4);
      areg  = *(const bf16x8*)(asrc + (step + 1) * 64);
    }
#pragma unroll
    for (int s = 0; s < 2; ++s) {
      const int chk = s * 4 + ksel;
      bf16x8 af  = *(const bf16x8*)((char*)At + a_tr  * 128 + ((chk ^ (a_tr  & 7)) << 4));
      bf16x8 wf0 = *(const bf16x8*)((char*)Wt + w_tr0 * 128 + ((chk ^ (w_tr0 & 7)) << 4));
      bf16x8 wf1 = *(const bf16x8*)((char*)Wt + w_tr1 * 128 + ((chk ^ (w_tr1 & 7)) << 4));
      acc[0] = __builtin_amdgcn_mfma_f32_16x16x32_bf16(af, wf0, acc[0], 0, 0, 0);
      acc[1] = __builtin_amdgcn_mfma_f32_16x16x32_bf16(af, wf1, acc[1], 0, 0, 0);
    }
  }
}

// ============ scores (+ h0 bf16 convert piggybacked) ============
// sc[b*256+pos] = dot(AO[pos,b,:], w_y)   (h_top@w_h + b_attn cancel in softmax)
__global__ __launch_bounds__(256) void k_pre(const float* __restrict__ AO,
                                             const float* __restrict__ Wattn,
                                             const float* __restrict__ h0,
                                             float* __restrict__ sc,
                                             __bf16* __restrict__ h0b) {
  if (blockIdx.x >= 4096) {
    const int base = ((int)blockIdx.x - 4096) * 256 + threadIdx.x;  // 65536 thr
#pragma unroll
    for (int i = 0; i < 4; ++i) {
      int idx = base + i * 65536;                 // float4 index, 262144 total
      float4 v = ((const float4*)h0)[idx];
      bf16x4 o;
      o[0] = (__bf16)v.x; o[1] = (__bf16)v.y; o[2] = (__bf16)v.z; o[3] = (__bf16)v.w;
      ((bf16x4*)h0b)[idx] = o;
    }
    return;
  }
  const int lane = threadIdx.x & 63, wave = threadIdx.x >> 6;
  const float* wy = Wattn + 1024;
  float4 wv[4];
#pragma unroll
  for (int q = 0; q < 4; ++q) wv[q] = *(const float4*)(wy + lane * 4 + 256 * q);
  const int row0 = (blockIdx.x * 4 + wave) * 4;
  float acc[4];
#pragma unroll
  for (int rr = 0; rr < 4; ++rr) {
    const float4* rp = (const float4*)(AO + (size_t)(row0 + rr) * 1024);
    float a = 0.f;
#pragma unroll
    for (int q = 0; q < 4; ++q) {
      float4 v = rp[lane + 64 * q];
      a += v.x * wv[q].x + v.y * wv[q].y + v.z * wv[q].z + v.w * wv[q].w;
    }
    acc[rr] = a;
  }
#pragma unroll
  for (int rr = 0; rr < 4; ++rr) {
    float a = acc[rr];
#pragma unroll
    for (int off = 32; off; off >>= 1) a += __shfl_xor(a, off, 64);
    if (lane == 0) {
      int row = row0 + rr;                       // row = pos*256 + b
      sc[(row & 255) * 256 + (row >> 8)] = a;    // [b][pos]
    }
  }
}

// ============ Gh[l] = h0b[l] @ Whh[l]^T + bih + bhh (all layers, parallel) ============
__global__ __launch_bounds__(512) void k_gh(const __bf16* __restrict__ h0b,
                                            const float* __restrict__ Whh0,
                                            const float* __restrict__ Whh_r,
                                            const float* __restrict__ bih0,
                                            const float* __restrict__ bhh0,
                                            const float* __restrict__ bih_r,
                                            const float* __restrict__ bhh_r,
                                            float* __restrict__ Gh) {
  __shared__ __bf16 At[64 * 64];
  __shared__ __bf16 Wt[64 * 64];
  const int l = blockIdx.x >> 8, inner = blockIdx.x & 255;
  const int cb = inner & 63, rb = inner >> 6;
  const int j0 = cb * 16, r0 = rb * 64;
  const __bf16* A = h0b + (size_t)l * 262144;
  const float* W  = (l == 0) ? Whh0 : (Whh_r + (size_t)(l - 1) * 4194304);
  const float* bi = (l == 0) ? bih0 : (bih_r + (size_t)(l - 1) * 4096);
  const float* bh = (l == 0) ? bhh0 : (bhh_r + (size_t)(l - 1) * 4096);
  f32x4 acc[2] = {};
  tile_gemm<1024>(A, W, r0, j0, At, Wt, acc);
  float* Go = Gh + (size_t)l * 1048576;
  const int lane = threadIdx.x & 63, wave = threadIdx.x >> 6;
  const int rf = wave & 3, gg = wave >> 2;
  const int col = j0 + (lane & 15);
  const int rbase = r0 + rf * 16 + ((lane >> 4) << 2);
#pragma unroll
  for (int gi = 0; gi < 2; ++gi) {
    const int cg = (gg * 2 + gi) * 1024 + col;
#pragma unroll
    for (int q = 0; q < 4; ++q)
      Go[(size_t)(rbase + q) * G4 + cg] = acc[gi][q] + bi[cg] + bh[cg];
  }
}

// ============ fused softmax + applied_last + embedding -> x (bf16) ============
__global__ __launch_bounds__(256) void k_smx(const float* __restrict__ sc,
                                             const float* __restrict__ AO,
                                             const float* __restrict__ inp,
                                             const float* __restrict__ Wemb,
                                             const float* __restrict__ bemb,
                                             float* __restrict__ norm_out,
                                             __bf16* __restrict__ x) {
  __shared__ float red[4];
  __shared__ float wsm[32];
  const int b = blockIdx.x, t = threadIdx.x, lane = t & 63, wave = t >> 6;
  float s = sc[b * 256 + t];
  float m = s;
#pragma unroll
  for (int off = 32; off; off >>= 1) m = fmaxf(m, __shfl_xor(m, off, 64));
  if (lane == 0) red[wave] = m;
  __syncthreads();
  m = fmaxf(fmaxf(red[0], red[1]), fmaxf(red[2], red[3]));
  float e = __expf(s - m);
  float sum = e;
#pragma unroll
  for (int off = 32; off; off >>= 1) sum += __shfl_xor(sum, off, 64);
  __syncthreads();
  if (lane == 0) red[wave] = sum;
  __syncthreads();
  sum = red[0] + red[1] + red[2] + red[3];
  float nv = e / sum;
  norm_out[b * 256 + t] = nv;
  if (t >= 224) wsm[t - 224] = nv;
  __syncthreads();
  float acc[4] = {0.f, 0.f, 0.f, 0.f};
  const float* base = AO + ((size_t)224 * 256 + b) * 1024;
#pragma unroll 4
  for (int i = 0; i < 32; ++i) {
    float w = wsm[i];
    const float* rp = base + (size_t)i * 256 * 1024;
#pragma unroll
    for (int q = 0; q < 4; ++q) acc[q] += w * rp[t + 256 * q];
  }
#pragma unroll
  for (int q = 0; q < 4; ++q) x[(size_t)b * KX + t + 256 * q] = (__bf16)(8.0f * acc[q]);
  float i0 = inp[b * 2], i1 = inp[b * 2 + 1];
#pragma unroll
  for (int r = 0; r < 2; ++r) {
    int j = t + 256 * r;
    float e2 = i0 * Wemb[j * 2] + i1 * Wemb[j * 2 + 1] + bemb[j];
    x[(size_t)b * KX + 1024 + j] = (__bf16)fmaxf(e2, 0.f);
  }
}

// ============ fused LSTM layer: GEMM + gates, writes h/c/hb ============
template<int K>
__global__ __launch_bounds__(512) void k_layer(const __bf16* __restrict__ A,
                                               const float* __restrict__ Wih,
                                               const float* __restrict__ Gh,
                                               const float* __restrict__ c0,
                                               float* __restrict__ h_out,
                                               float* __restrict__ c_out,
                                               __bf16* __restrict__ hb) {
  __shared__ __bf16 At[64 * 64];
  __shared__ __bf16 Wt[64 * 64];
  __shared__ float exch[4][2][256];
  const int t = threadIdx.x, lane = t & 63, wave = t >> 6;
  const int rf = wave & 3, gg = wave >> 2;
  const int cb = blockIdx.x & 63, rb = blockIdx.x >> 6;
  const int j0 = cb * 16, r0 = rb * 64;
  f32x4 acc[2] = {};
  tile_gemm<K>(A, Wih, r0, j0, At, Wt, acc);
  const int col = j0 + (lane & 15);
  const int rbase = r0 + rf * 16 + ((lane >> 4) << 2);
  // add Gh (h0 @ Whh^T + biases) for this wave's two gates
#pragma unroll
  for (int gi = 0; gi < 2; ++gi) {
    const float* gp = Gh + (size_t)rbase * G4 + (gg * 2 + gi) * 1024 + col;
#pragma unroll
    for (int q = 0; q < 4; ++q) acc[gi][q] += gp[(size_t)q * G4];
  }
  const int eidx = ((lane >> 4) << 2) * 16 + (lane & 15);
  if (gg == 1) {
#pragma unroll
    for (int gi = 0; gi < 2; ++gi)
#pragma unroll
      for (int q = 0; q < 4; ++q)
        exch[rf][gi][eidx + q * 16] = acc[gi][q];
  }
  __syncthreads();
  if (gg == 0) {
#pragma unroll
    for (int q = 0; q < 4; ++q) {
      const int b = rbase + q;
      float gv = exch[rf][0][eidx + q * 16];
      float ov = exch[rf][1][eidx + q * 16];
      float si = 1.f / (1.f + __expf(-acc[0][q]));
      float sf = 1.f / (1.f + __expf(-acc[1][q]));
      float so = 1.f / (1.f + __expf(-ov));
      float c2 = sf * c0[(size_t)b * 1024 + col] + si * tanhf(gv);
      float h2 = so * tanhf(c2);
      h_out[(size_t)b * 1024 + col] = h2;
      c_out[(size_t)b * 1024 + col] = c2;
      hb[(size_t)b * 1024 + col] = (__bf16)h2;
    }
  }
}

// ============ final output ============
__global__ __launch_bounds__(256) void k_final(const float* __restrict__ h3,
                                               const float* __restrict__ Wout,
                                               const float* __restrict__ bout,
                                               float* __restrict__ out) {
  const int lane = threadIdx.x & 63, wave = threadIdx.x >> 6;
  const int b = blockIdx.x * 4 + wave;
  const float4* hp = (const float4*)(h3 + (size_t)b * 1024);
  const float4* w0 = (const float4*)Wout;
  const float4* w1 = (const float4*)(Wout + 1024);
  float a0 = 0.f, a1 = 0.f;
#pragma unroll
  for (int q = 0; q < 4; ++q) {
    float4 hv = hp[lane + 64 * q];
    float4 v0 = w0[lane + 64 * q];
    float4 v1 = w1[lane + 64 * q];
    a0 += hv.x * v0.x + hv.y * v0.y + hv.z * v0.z + hv.w * v0.w;
    a1 += hv.x * v1.x + hv.y * v1.y + hv.z * v1.z + hv.w * v1.w;
  }
#pragma unroll
  for (int off = 32; off; off >>= 1) {
    a0 += __shfl_xor(a0, off, 64);
    a1 += __shfl_xor(a1, off, 64);
  }
  if (lane == 0) {
    out[b * 2]     = a0 + bout[0];
    out[b * 2 + 1] = a1 + bout[1];
  }
}

extern "C" void kernel_launch(void* const* d_in, const int* in_sizes, int n_in,
                              void* d_out, int out_size, void* d_ws, size_t ws_size,
                              hipStream_t stream) {
  const float* inp    = (const float*)d_in[0];
  const float* h0     = (const float*)d_in[1];
  const float* c0     = (const float*)d_in[2];
  const float* AO     = (const float*)d_in[3];
  const float* Wemb   = (const float*)d_in[4];
  const float* bemb   = (const float*)d_in[5];
  const float* Wattn  = (const float*)d_in[6];
  // d_in[7] = b_attn (cancels in softmax)
  const float* Wih0   = (const float*)d_in[8];
  const float* Whh0   = (const float*)d_in[9];
  const float* bih0   = (const float*)d_in[10];
  const float* bhh0   = (const float*)d_in[11];
  const float* Wih_r  = (const float*)d_in[12];
  const float* Whh_r  = (const float*)d_in[13];
  const float* bih_r  = (const float*)d_in[14];
  const float* bhh_r  = (const float*)d_in[15];
  const float* Wout   = (const float*)d_in[16];
  const float* bout   = (const float*)d_in[17];

  float* out = (float*)d_out;
  char* ws = (char*)d_ws;

  float*  sc  = (float*)(ws + 0);                  // 256 KB
  float*  Gh  = (float*)(ws + (1u << 18));         // 16 MB (4 layers)
  __bf16* xb  = (__bf16*)(ws + 17039360);          // 768 KB
  __bf16* h0b = (__bf16*)(ws + 17825792);          // 2 MB
  __bf16* hb  = (__bf16*)(ws + 19922944);          // 2 MB (4 layers x 512 KB)

  k_pre<<<4352, 256, 0, stream>>>(AO, Wattn, h0, sc, h0b);
  k_gh<<<1024, 512, 0, stream>>>(h0b, Whh0, Whh_r, bih0, bhh0, bih_r, bhh_r, Gh);
  k_smx<<<256, 256, 0, stream>>>(sc, AO, inp, Wemb, bemb, out + O_NORM, xb);

  for (int l = 0; l < 4; ++l) {
    const __bf16* A1 = (l == 0) ? xb : (hb + (size_t)(l - 1) * 262144);
    float* h_out = out + O_H + (size_t)l * 262144;
    float* c_out = out + O_C + (size_t)l * 262144;
    if (l == 0)
      k_layer<1536><<<256, 512, 0, stream>>>(A1, Wih0, Gh, c0, h_out, c_out, hb);
    else
      k_layer<1024><<<256, 512, 0, stream>>>(A1, Wih_r + (size_t)(l - 1) * 4194304,
                                             Gh + (size_t)l * 1048576,
                                             c0 + (size_t)l * 262144,
                                             h_out, c_out,
                                             hb + (size_t)l * 262144);
  }

  k_final<<<64, 256, 0, stream>>>(out + O_H + 3 * 262144, Wout, bout, out + O_FINAL);
}